// Round 1
// baseline (78.157 us; speedup 1.0000x reference)
//
#include <hip/hip_runtime.h>

// out[b,h,w,o] = sum_{s1..s4} core[s1,s2,s3,s4,o] * a[s1]*b[s2]*c[s3]*d[s4]
// a = inp[b, h,   w,   :], b = inp[b, h,   w+1, :]
// c = inp[b, h+1, w,   :], d = inp[b, h+1, w+1, :]
// input shape (1,128,128,128,2) fp32; core (2,2,2,2,4) fp32; out (128,127,127,4) fp32.

#define NB 128
#define NH 128
#define NW 128
#define HN 127
#define WN 127

__global__ __launch_bounds__(128) void eps_kernel(const float* __restrict__ inp,
                                                  const float* __restrict__ core,
                                                  float* __restrict__ out) {
    __shared__ float cs[64];
    const int tid = threadIdx.x;
    if (tid < 64) cs[tid] = core[tid];
    __syncthreads();

    const int h = blockIdx.x;   // 0..126
    const int b = blockIdx.y;   // 0..127
    const int w = tid;          // 0..127, 127 inactive
    if (w >= WN) return;

    const float* row0 = inp + ((size_t)(b * NH + h) * NW + w) * 2;
    const float* row1 = row0 + (size_t)NW * 2;

    // two float2 loads per row: (a0,a1) at w, (b0,b1) at w+1 — 8B aligned
    float2 av = *(const float2*)(row0);
    float2 bv = *(const float2*)(row0 + 2);
    float2 cv = *(const float2*)(row1);
    float2 dv = *(const float2*)(row1 + 2);

    // ab[s1*2+s2], cd[s3*2+s4]
    float ab[4] = {av.x * bv.x, av.x * bv.y, av.y * bv.x, av.y * bv.y};
    float cd[4] = {cv.x * dv.x, cv.x * dv.y, cv.y * dv.x, cv.y * dv.y};

    float4 acc = make_float4(0.f, 0.f, 0.f, 0.f);
    #pragma unroll
    for (int i = 0; i < 4; ++i) {
        #pragma unroll
        for (int j = 0; j < 4; ++j) {
            const float wt = ab[i] * cd[j];
            // core index: ((s1*2+s2)*2+s3)*2+s4)*4 + o = (i*4+j)*4 + o
            const float* cr = &cs[(i * 4 + j) * 4];
            acc.x += wt * cr[0];
            acc.y += wt * cr[1];
            acc.z += wt * cr[2];
            acc.w += wt * cr[3];
        }
    }

    const size_t oidx = ((size_t)(b * HN + h) * WN + w) * 4;  // 16B aligned
    *(float4*)(out + oidx) = acc;
}

extern "C" void kernel_launch(void* const* d_in, const int* in_sizes, int n_in,
                              void* d_out, int out_size, void* d_ws, size_t ws_size,
                              hipStream_t stream) {
    const float* inp  = (const float*)d_in[0];
    const float* core = (const float*)d_in[1];
    float* out = (float*)d_out;
    dim3 grid(HN, NB);  // (127, 128)
    eps_kernel<<<grid, 128, 0, stream>>>(inp, core, out);
}